// Round 12
// baseline (467.808 us; speedup 1.0000x reference)
//
#include <hip/hip_runtime.h>
#include <hip/hip_bf16.h>

#define HF 128   // feature/hidden dim (F == H == 128)
#define BSH 8    // bucket shift: 256 nodes per bucket
#define BSZ 256
#define NBMAX 1024
#define FCAP 8192
#define AST 136  // padded LDS row stride (bf16 elems; 272 B)
#define WST 136  // fp8 W row stride in bytes (8-aligned)
#define HB 512   // histogram/bin blocks

typedef __attribute__((ext_vector_type(8))) short bf16x8;
typedef __attribute__((ext_vector_type(4))) float f32x4;
typedef __attribute__((ext_vector_type(2))) float f32x2;

__device__ inline float bflo(unsigned u) { return __uint_as_float(u << 16); }
__device__ inline float bfhi(unsigned u) { return __uint_as_float(u & 0xffff0000u); }
__device__ inline unsigned short f2bf(float f) {
    unsigned u = __float_as_uint(f);
    unsigned r = (u + 0x7fffu + ((u >> 16) & 1u)) >> 16;
    return (unsigned short)r;
}
__device__ inline unsigned pack2(float a, float b) {
    return (unsigned)f2bf(a) | ((unsigned)f2bf(b) << 16);
}
// pack 8 floats -> 8 fp8 e4m3 (uint2)
__device__ inline uint2 pk8_fp8(const float* v) {
    int a = __builtin_amdgcn_cvt_pk_fp8_f32(v[0], v[1], 0, 0);
    a = __builtin_amdgcn_cvt_pk_fp8_f32(v[2], v[3], a, 1);
    int b = __builtin_amdgcn_cvt_pk_fp8_f32(v[4], v[5], 0, 0);
    b = __builtin_amdgcn_cvt_pk_fp8_f32(v[6], v[7], b, 1);
    uint2 r; r.x = (unsigned)a; r.y = (unsigned)b;
    return r;
}
__device__ inline long long u2ll(uint2 q) {
    return (long long)(((unsigned long long)q.y << 32) | (unsigned long long)q.x);
}

// ============ mega-init: cast_x(bf16+fp8) | cast_wt(fp8) | hist | bounds | zero
__global__ __launch_bounds__(256) void init_all(
    const float* __restrict__ x, unsigned short* __restrict__ xb,
    unsigned char* __restrict__ x8, int castBlk, int nchunks,
    const float* __restrict__ w0, const float* __restrict__ w1,
    const float* __restrict__ w2, const float* __restrict__ w3,
    unsigned char* __restrict__ Wt8All,
    const int* __restrict__ dst, int* __restrict__ bpart, int E, int chunkH,
    const int* __restrict__ batch, int* __restrict__ gstart, int N, int Gn, int nBlocks,
    float* __restrict__ Szero, float* __restrict__ outm)
{
    __shared__ int lh[NBMAX];
    int b = blockIdx.x;
    int t = threadIdx.x;
    if (b < castBlk) {                       // ---- cast x -> bf16 + fp8
        int i = b * 256 + t;
        if (i < nchunks) {
            float4 a = ((const float4*)x)[2 * i];
            float4 c = ((const float4*)x)[2 * i + 1];
            uint4 o;
            o.x = pack2(a.x, a.y); o.y = pack2(a.z, a.w);
            o.z = pack2(c.x, c.y); o.w = pack2(c.z, c.w);
            ((uint4*)xb)[i] = o;
            float v[8] = {a.x, a.y, a.z, a.w, c.x, c.y, c.z, c.w};
            ((uint2*)x8)[i] = pk8_fp8(v);
        }
        return;
    }
    b -= castBlk;
    if (b < 4) {                             // ---- transpose-cast weights -> fp8
        const float* W = (b == 0) ? w0 : (b == 1) ? w1 : (b == 2) ? w2 : w3;
        unsigned char* O = Wt8All + b * 16384;
        for (int idx = t; idx < 16384; idx += 256) {
            int n = idx >> 7, k = idx & 127;
            float wv = W[k * 128 + n];
            int r = __builtin_amdgcn_cvt_pk_fp8_f32(wv, wv, 0, 0);
            O[idx] = (unsigned char)(r & 0xff);
        }
        return;
    }
    b -= 4;
    if (b < HB) {                            // ---- histogram partials (transposed write)
        int NBl = (N + BSZ - 1) >> BSH;
        for (int i = t; i < NBl; i += 256) lh[i] = 0;
        __syncthreads();
        int beg = b * chunkH;
        int end = min(E, beg + chunkH);
        for (int e = beg + t; e < end; e += 256)
            atomicAdd(&lh[dst[e] >> BSH], 1);
        __syncthreads();
        for (int i = t; i < NBl; i += 256) bpart[i * HB + b] = lh[i];
        return;
    }
    b -= HB;
    if (b < nBlocks) {                       // ---- graph bounds
        int i = b * 256 + t;
        if (i >= N) return;
        int bi = batch[i];
        int bp = (i == 0) ? -1 : batch[i - 1];
        for (int g = bp + 1; g <= bi; g++) gstart[g] = i;
        if (i == N - 1)
            for (int g = bi + 1; g <= Gn; g++) gstart[g] = N;
        return;
    }
    if (t < 2 * HF) { Szero[t] = 0.f; Szero[t + 2 * HF] = 0.f; }
    if (t == 0) outm[0] = 0.f;
}

// ============ scan: bucket totals + boff/bcur ================================
__global__ void scanp(const int* __restrict__ bpart, int* __restrict__ boff,
                      int* __restrict__ bcur, int NB, int E)
{
    __shared__ int tot[NBMAX];
    __shared__ int part[256];
    int t = threadIdx.x;
    for (int i = t; i < NB; i += 256) {
        const int4* pp = (const int4*)(bpart + (size_t)i * HB);
        int run = 0;
#pragma unroll 4
        for (int b = 0; b < HB / 4; b++) {
            int4 v = pp[b];
            run += v.x + v.y + v.z + v.w;
        }
        tot[i] = run;
    }
    __syncthreads();
    int v[4];
    int s = 0;
#pragma unroll
    for (int i = 0; i < 4; i++) {
        int idx = t * 4 + i;
        v[i] = (idx < NB) ? tot[idx] : 0;
        s += v[i];
    }
    part[t] = s;
    __syncthreads();
    for (int o = 1; o < 256; o <<= 1) {
        int y = (t >= o) ? part[t - o] : 0;
        __syncthreads();
        part[t] += y;
        __syncthreads();
    }
    int base = part[t] - s;
#pragma unroll
    for (int i = 0; i < 4; i++) {
        int idx = t * 4 + i;
        if (idx < NB) { boff[idx] = base; bcur[idx] = base; base += v[i]; }
    }
    if (t == 0) boff[NB] = E;
}

// ============ bin edges =====================================================
__global__ __launch_bounds__(256) void bucket_bin(
    const int* __restrict__ src, const int* __restrict__ dst,
    int* __restrict__ bcur, unsigned* __restrict__ ebuf, int E, int NB, int chunkH)
{
    __shared__ int lh[NBMAX];
    int t = threadIdx.x;
    for (int i = t; i < NB; i += 256) lh[i] = 0;
    __syncthreads();
    int beg = blockIdx.x * chunkH;
    int end = min(E, beg + chunkH);
    for (int e = beg + t; e < end; e += 256)
        atomicAdd(&lh[dst[e] >> BSH], 1);
    __syncthreads();
    for (int i = t; i < NB; i += 256) {
        int c = lh[i];
        lh[i] = c ? atomicAdd(&bcur[i], c) : 0;
    }
    __syncthreads();
    for (int e = beg + t; e < end; e += 256) {
        int d = dst[e];
        int b = d >> BSH;
        int pos = atomicAdd(&lh[b], 1);
        ebuf[pos] = ((unsigned)src[e] << BSH) | (unsigned)(d & (BSZ - 1));
    }
}

// ============ per-bucket fill ================================================
__global__ __launch_bounds__(256) void bucket_fill(
    const unsigned* __restrict__ ebuf, const int* __restrict__ boff,
    int* __restrict__ off, int* __restrict__ esrc, int N, int NB, int E)
{
    __shared__ int deg[BSZ];
    __shared__ int pref[BSZ];
    __shared__ int lcur[BSZ];
    __shared__ int lsr[FCAP];
    int b = blockIdx.x;
    int t = threadIdx.x;
    int segBeg = boff[b], segEnd = boff[b + 1];
    int segLen = segEnd - segBeg;
    int node0 = b << BSH;
    deg[t] = 0;
    __syncthreads();
    for (int i = segBeg + t; i < segEnd; i += 256)
        atomicAdd(&deg[ebuf[i] & (BSZ - 1)], 1);
    __syncthreads();
    int dv = deg[t];
    pref[t] = dv;
    __syncthreads();
    for (int o = 1; o < 256; o <<= 1) {
        int y = (t >= o) ? pref[t - o] : 0;
        __syncthreads();
        pref[t] += y;
        __syncthreads();
    }
    int excl = pref[t] - dv;
    int node = node0 + t;
    if (node < N) off[node] = segBeg + excl;
    lcur[t] = excl;
    if (b == NB - 1 && t == 0) off[N] = E;
    __syncthreads();
    if (segLen <= FCAP) {
        for (int i = segBeg + t; i < segEnd; i += 256) {
            unsigned v = ebuf[i];
            int slot = atomicAdd(&lcur[v & (BSZ - 1)], 1);
            lsr[slot] = (int)(v >> BSH);
        }
        __syncthreads();
        for (int i = t; i < segLen; i += 256) esrc[segBeg + i] = lsr[i];
    } else {
        for (int i = segBeg + t; i < segEnd; i += 256) {
            unsigned v = ebuf[i];
            int slot = atomicAdd(&lcur[v & (BSZ - 1)], 1);
            esrc[segBeg + slot] = (int)(v >> BSH);
        }
    }
}

// ============ gather: neighbors from fp8 table; U emitted as fp8 ============
// FOLD=false: self-term from bf16 xb. FOLD=true: self-term from the fp8 table,
// BN1 scale/shift computed inline.
template <bool FOLD>
__global__ __launch_bounds__(256) void gather_u(
    const unsigned short* __restrict__ xb, const unsigned char* __restrict__ x8,
    const int* __restrict__ off, const int* __restrict__ esrc,
    const float* __restrict__ epsp,
    const float* __restrict__ S1, const float* __restrict__ S2,
    const float* __restrict__ gamma, const float* __restrict__ beta, float invN,
    unsigned char* __restrict__ U8, int N)
{
    __shared__ float lsc[HF], lsh[HF];
    int tid = threadIdx.x;
    if (FOLD) {
        if (tid < HF) {
            float mu = S1[tid] * invN;
            float var = S2[tid] * invN - mu * mu;
            float rs = rsqrtf(var + 1e-5f);
            float sc = gamma[tid] * rs;
            lsc[tid] = sc;
            lsh[tid] = beta[tid] - mu * sc;
        }
        __syncthreads();
    }
    int lane16 = tid & 15;
    int node = (blockIdx.x * 256 + tid) >> 4;
    if (node >= N) return;
    int beg = off[node], end = off[node + 1];
    float acc[8] = {0.f, 0.f, 0.f, 0.f, 0.f, 0.f, 0.f, 0.f};
    for (int j0 = beg; j0 < end; j0 += 16) {
        int myidx = (j0 + lane16 < end) ? esrc[j0 + lane16] : 0;
        int cnt = min(16, end - j0);
        for (int t = 0; t < cnt; t++) {
            int s = __shfl(myidx, t, 16);
            uint2 p = *(const uint2*)(x8 + (size_t)s * HF + lane16 * 8);
            f32x2 f0 = __builtin_amdgcn_cvt_pk_f32_fp8((int)p.x, 0);
            f32x2 f1 = __builtin_amdgcn_cvt_pk_f32_fp8((int)p.x, 1);
            f32x2 f2 = __builtin_amdgcn_cvt_pk_f32_fp8((int)p.y, 0);
            f32x2 f3 = __builtin_amdgcn_cvt_pk_f32_fp8((int)p.y, 1);
            acc[0] += f0.x; acc[1] += f0.y;
            acc[2] += f1.x; acc[3] += f1.y;
            acc[4] += f2.x; acc[5] += f2.y;
            acc[6] += f3.x; acc[7] += f3.y;
        }
    }
    float ep = 1.0f + epsp[0];
    if (FOLD) {   // self-term from fp8 table (h8)
        uint2 sp = *(const uint2*)(x8 + (size_t)node * HF + lane16 * 8);
        f32x2 f0 = __builtin_amdgcn_cvt_pk_f32_fp8((int)sp.x, 0);
        f32x2 f1 = __builtin_amdgcn_cvt_pk_f32_fp8((int)sp.x, 1);
        f32x2 f2 = __builtin_amdgcn_cvt_pk_f32_fp8((int)sp.y, 0);
        f32x2 f3 = __builtin_amdgcn_cvt_pk_f32_fp8((int)sp.y, 1);
        acc[0] += ep * f0.x; acc[1] += ep * f0.y;
        acc[2] += ep * f1.x; acc[3] += ep * f1.y;
        acc[4] += ep * f2.x; acc[5] += ep * f2.y;
        acc[6] += ep * f3.x; acc[7] += ep * f3.y;
        float cf = ep + (float)(end - beg);
        const float4 s0 = *(const float4*)(&lsc[lane16 * 8]);
        const float4 s1 = *(const float4*)(&lsc[lane16 * 8 + 4]);
        const float4 h0 = *(const float4*)(&lsh[lane16 * 8]);
        const float4 h1 = *(const float4*)(&lsh[lane16 * 8 + 4]);
        acc[0] = acc[0] * s0.x + h0.x * cf; acc[1] = acc[1] * s0.y + h0.y * cf;
        acc[2] = acc[2] * s0.z + h0.z * cf; acc[3] = acc[3] * s0.w + h0.w * cf;
        acc[4] = acc[4] * s1.x + h1.x * cf; acc[5] = acc[5] * s1.y + h1.y * cf;
        acc[6] = acc[6] * s1.z + h1.z * cf; acc[7] = acc[7] * s1.w + h1.w * cf;
    } else {      // self-term from bf16 xb (exact)
        uint4 xx = *(const uint4*)(xb + (size_t)node * HF + lane16 * 8);
        acc[0] += ep * bflo(xx.x); acc[1] += ep * bfhi(xx.x);
        acc[2] += ep * bflo(xx.y); acc[3] += ep * bfhi(xx.y);
        acc[4] += ep * bflo(xx.z); acc[5] += ep * bfhi(xx.z);
        acc[6] += ep * bflo(xx.w); acc[7] += ep * bfhi(xx.w);
    }
    *(uint2*)(U8 + (size_t)node * HF + lane16 * 8) = pk8_fp8(acc);
}

// ====== double-GEMM, fp8 operands, bf16 T in LDS, fp32 acc ======
// Wave = 16 rows x 128 cols. lW = fp8 W (17.4 KB), lT = bf16 T/C (17.4 KB).
// EMIT_BF16: layer2 emits bf16 Hp; else layer1 emits fp8 h8 only.
template <bool EMIT_BF16>
__global__ __launch_bounds__(256) void gemm2F(
    const unsigned char* __restrict__ U8,
    const unsigned char* __restrict__ Wt8a, const float* __restrict__ ba,
    const unsigned char* __restrict__ Wt8b, const float* __restrict__ bb,
    unsigned short* __restrict__ out, unsigned char* __restrict__ out8,
    float* __restrict__ S1, float* __restrict__ S2, int n)
{
    __shared__ unsigned char lW[128 * WST];
    __shared__ unsigned short lT[64 * AST];
    __shared__ float lS1[HF], lS2[HF];
    int tid = threadIdx.x;
    int w = tid >> 6, lane = tid & 63;
    int m = lane & 15, quad = lane >> 4;
    int row0 = blockIdx.x * 64;
    if (tid < HF) { lS1[tid] = 0.f; lS2[tid] = 0.f; }

    // hoist A-frag global loads (independent of LDS staging)
    int arow = row0 + w * 16 + m;
    if (arow >= n) arow = n - 1;                  // clamp; guarded below
    long long aF[4];
#pragma unroll
    for (int kk = 0; kk < 4; kk++)
        aF[kk] = *(const long long*)(U8 + (size_t)arow * HF + kk * 32 + quad * 8);

    for (int c = tid; c < 2048; c += 256) {       // Wa8 -> lW
        int r = c >> 4, k8 = c & 15;
        *(uint2*)(&lW[r * WST + k8 * 8]) = *(const uint2*)(Wt8a + r * HF + k8 * 8);
    }
    __syncthreads();

    f32x4 acc[8];
#pragma unroll
    for (int nt = 0; nt < 8; nt++) acc[nt] = (f32x4){0.f, 0.f, 0.f, 0.f};
#pragma unroll
    for (int nt = 0; nt < 8; nt++) {
#pragma unroll
        for (int kk = 0; kk < 4; kk++) {
            long long b = *(const long long*)(&lW[(nt * 16 + m) * WST + kk * 32 + quad * 8]);
            acc[nt] = __builtin_amdgcn_mfma_f32_16x16x32_fp8_fp8(aF[kk], b, acc[nt], 0, 0, 0);
        }
    }
    // T = relu(acc+ba) -> lT bf16 (own rows)
#pragma unroll
    for (int nt = 0; nt < 8; nt++) {
        float bav = ba[nt * 16 + m];
#pragma unroll
        for (int r = 0; r < 4; r++) {
            int lrow = w * 16 + quad * 4 + r;
            lT[lrow * AST + nt * 16 + m] = f2bf(fmaxf(acc[nt][r] + bav, 0.f));
        }
    }
    __syncthreads();                               // all waves done with lW (Wa)
    for (int c = tid; c < 2048; c += 256) {        // Wb8 -> lW
        int r = c >> 4, k8 = c & 15;
        *(uint2*)(&lW[r * WST + k8 * 8]) = *(const uint2*)(Wt8b + r * HF + k8 * 8);
    }
    __syncthreads();

    // stage-2 A-frags: read own bf16 T rows, convert to fp8 in regs
#pragma unroll
    for (int kk = 0; kk < 4; kk++) {
        uint4 tv = *(const uint4*)(&lT[(w * 16 + m) * AST + kk * 32 + quad * 8]);
        float f[8] = {bflo(tv.x), bfhi(tv.x), bflo(tv.y), bfhi(tv.y),
                      bflo(tv.z), bfhi(tv.z), bflo(tv.w), bfhi(tv.w)};
        aF[kk] = u2ll(pk8_fp8(f));
    }
#pragma unroll
    for (int nt = 0; nt < 8; nt++) acc[nt] = (f32x4){0.f, 0.f, 0.f, 0.f};
#pragma unroll
    for (int nt = 0; nt < 8; nt++) {
#pragma unroll
        for (int kk = 0; kk < 4; kk++) {
            long long b = *(const long long*)(&lW[(nt * 16 + m) * WST + kk * 32 + quad * 8]);
            acc[nt] = __builtin_amdgcn_mfma_f32_16x16x32_fp8_fp8(aF[kk], b, acc[nt], 0, 0, 0);
        }
    }
    // epilogue: relu + stats + C -> lT own rows (bf16), vectorized store
#pragma unroll
    for (int nt = 0; nt < 8; nt++) {
        int col = nt * 16 + m;
        float bbv = bb[col];
        float cs = 0.f, cq = 0.f;
#pragma unroll
        for (int r = 0; r < 4; r++) {
            int lrow = w * 16 + quad * 4 + r;
            int grow = row0 + lrow;
            float v = fmaxf(acc[nt][r] + bbv, 0.f);
            lT[lrow * AST + col] = f2bf(v);
            if (grow < n) { cs += v; cq += v * v; }
        }
        cs += __shfl_down(cs, 32); cs += __shfl_down(cs, 16);
        cq += __shfl_down(cq, 32); cq += __shfl_down(cq, 16);
        if (quad == 0) { atomicAdd(&lS1[col], cs); atomicAdd(&lS2[col], cq); }
    }
#pragma unroll
    for (int i = 0; i < 4; i++) {
        int idx = i * 64 + lane;
        int r = idx >> 4, k16 = idx & 15;
        int grow = row0 + w * 16 + r;
        if (grow < n) {
            uint4 v = *(const uint4*)(&lT[(w * 16 + r) * AST + k16 * 8]);
            if (EMIT_BF16) {
                *(uint4*)(out + (size_t)grow * HF + k16 * 8) = v;
            } else {
                float f[8] = {bflo(v.x), bfhi(v.x), bflo(v.y), bfhi(v.y),
                              bflo(v.z), bfhi(v.z), bflo(v.w), bfhi(v.w)};
                *(uint2*)(out8 + (size_t)grow * HF + k16 * 8) = pk8_fp8(f);
            }
        }
    }
    __syncthreads();
    if (tid < HF) { atomicAdd(&S1[tid], lS1[tid]); atomicAdd(&S2[tid], lS2[tid]); }
}

// ---- pool (BN2 inline) + lin1 + mse (atomic) + heads, one kernel/graph ----
__global__ __launch_bounds__(512) void pool_tail(
    const unsigned short* __restrict__ h2raw,
    const float* __restrict__ S1, const float* __restrict__ S2,
    const float* __restrict__ gamma, const float* __restrict__ beta, float invN,
    const int* __restrict__ gstart, const float* __restrict__ W,
    const float* __restrict__ bias,
    const float* __restrict__ Wloss, const float* __restrict__ blossp,
    const float* __restrict__ degree,
    const float* __restrict__ W2, const float* __restrict__ b2,
    const float* __restrict__ W4, const float* __restrict__ b4,
    float* __restrict__ out1, float* __restrict__ out3,
    float* __restrict__ outm, int C_, int D_)
{
    __shared__ float lsc[HF], lsh[HF];
    __shared__ float red[8][HF];
    __shared__ float gv[HF];
    __shared__ float part[4][HF];
    __shared__ float wred[8];
    __shared__ float zz[HF];
    __shared__ float logits[16];
    __shared__ float lse_s;
    int gid = blockIdx.x;
    int t = threadIdx.x;
    if (t < HF) {
        float mu = S1[t] * invN;
        float var = S2[t] * invN - mu * mu;
        float rs = rsqrtf(var + 1e-5f);
        float sc = gamma[t] * rs;
        lsc[t] = sc;
        lsh[t] = beta[t] - mu * sc;
    }
    __syncthreads();
    int c2 = t & 63;
    int rg = t >> 6;
    int b = gstart[gid], e = gstart[gid + 1];
    float wla = lsc[2 * c2] * Wloss[2 * c2];
    float wlb = lsc[2 * c2 + 1] * Wloss[2 * c2 + 1];
    float c0l = lsh[2 * c2] * Wloss[2 * c2] + lsh[2 * c2 + 1] * Wloss[2 * c2 + 1];
    float bl = blossp[0];
    float s0 = 0.f, s1 = 0.f, macc = 0.f;
    for (int r = b + rg; r < e; r += 8) {
        unsigned u = *(const unsigned*)(h2raw + (size_t)r * HF + c2 * 2);
        float v0 = bflo(u), v1 = bfhi(u);
        s0 += v0; s1 += v1;
        float m = v0 * wla + v1 * wlb + c0l;
#pragma unroll
        for (int o = 32; o > 0; o >>= 1) m += __shfl_down(m, o);
        if (c2 == 0) {
            float d = m + bl - degree[r];
            macc += d * d;
        }
    }
    red[rg][c2 * 2] = s0;
    red[rg][c2 * 2 + 1] = s1;
    if (c2 == 0) wred[rg] = macc;
    __syncthreads();
    if (t < HF) {
        float s = red[0][t] + red[1][t] + red[2][t] + red[3][t]
                + red[4][t] + red[5][t] + red[6][t] + red[7][t];
        gv[t] = (e > b) ? lsc[t] * (s / (float)(e - b)) + lsh[t] : 0.f;
    }
    __syncthreads();
    int c = t & 127, kg = t >> 7;
    float a = 0.f;
#pragma unroll 8
    for (int k = kg * 32; k < kg * 32 + 32; k++) a += gv[k] * W[(size_t)k * HF + c];
    part[kg][c] = a;
    __syncthreads();
    if (t < HF) {
        float aa = part[0][t] + part[1][t] + part[2][t] + part[3][t] + bias[t];
        zz[t] = fmaxf(aa, 0.f);
    }
    if (t == 0) {
        float ps = wred[0] + wred[1] + wred[2] + wred[3]
                 + wred[4] + wred[5] + wred[6] + wred[7];
        atomicAdd(outm, ps * invN);
    }
    __syncthreads();
    if (t < C_) {
        float aa = b2[t];
        for (int k = 0; k < HF; k++) aa += zz[k] * W2[(size_t)k * C_ + t];
        logits[t] = aa;
    }
    __syncthreads();
    if (t == 0) {
        float mx = -1e30f;
        for (int i = 0; i < C_; i++) mx = fmaxf(mx, logits[i]);
        float s = 0.f;
        for (int i = 0; i < C_; i++) s += expf(logits[i] - mx);
        lse_s = mx + logf(s);
    }
    __syncthreads();
    if (t < C_) out1[(size_t)gid * C_ + t] = logits[t] - lse_s;
    if (t < D_) {
        float aa = b4[t];
        for (int k = 0; k < HF; k++) aa += zz[k] * W4[(size_t)k * D_ + t];
        out3[(size_t)gid * D_ + t] = aa;
    }
}

extern "C" void kernel_launch(void* const* d_in, const int* in_sizes, int n_in,
                              void* d_out, int out_size, void* d_ws, size_t ws_size,
                              hipStream_t stream)
{
    const float* x      = (const float*)d_in[0];
    const int*   ei     = (const int*)d_in[1];
    const int*   batch  = (const int*)d_in[2];
    const float* degree = (const float*)d_in[3];
    const float* eps1   = (const float*)d_in[4];
    const float* W1a    = (const float*)d_in[5];
    const float* b1a    = (const float*)d_in[6];
    const float* W1b    = (const float*)d_in[7];
    const float* b1b    = (const float*)d_in[8];
    const float* g1     = (const float*)d_in[9];
    const float* be1    = (const float*)d_in[10];
    const float* eps2   = (const float*)d_in[11];
    const float* W2a    = (const float*)d_in[12];
    const float* b2a    = (const float*)d_in[13];
    const float* W2b    = (const float*)d_in[14];
    const float* b2b    = (const float*)d_in[15];
    const float* g2     = (const float*)d_in[16];
    const float* be2    = (const float*)d_in[17];
    const float* Wlin1  = (const float*)d_in[18];
    const float* blin1  = (const float*)d_in[19];
    const float* Wlin2  = (const float*)d_in[20];
    const float* blin2  = (const float*)d_in[21];
    const float* Wlin4  = (const float*)d_in[22];
    const float* blin4  = (const float*)d_in[23];
    const float* Wloss  = (const float*)d_in[24];
    const float* bloss  = (const float*)d_in[25];

    const int N  = in_sizes[0] / HF;
    const int E  = in_sizes[1] / 2;
    const int C_ = in_sizes[21];
    const int D_ = in_sizes[23];
    const int Gn = (out_size - 1) / (C_ + D_);
    const int NB = (N + BSZ - 1) >> BSH;

    const int* src = ei;
    const int* dst = ei + E;

    size_t NH = (size_t)N * HF;
    char* p = (char*)d_ws;
    unsigned short* xb  = (unsigned short*)p; p += NH * 2;
    unsigned short* Hp2 = (unsigned short*)p; p += NH * 2;
    unsigned char*  U8  = (unsigned char*)p; p += NH;
    unsigned char*  x8  = (unsigned char*)p; p += NH;      // fp8 x
    unsigned char*  h8  = (unsigned char*)p; p += NH;      // fp8 h1
    unsigned char*  Wt8All = (unsigned char*)p; p += 4 * 16384;
    float* S1a  = (float*)p; p += HF * 4;     // [S1a S2a S1b S2b] contiguous
    float* S2a  = (float*)p; p += HF * 4;
    float* S1b  = (float*)p; p += HF * 4;
    float* S2b  = (float*)p; p += HF * 4;
    int* gstart = (int*)p; p += (Gn + 1) * 4;
    int* boff   = (int*)p; p += (NBMAX + 1) * 4;
    int* bcur   = (int*)p; p += NBMAX * 4;
    int* bpart  = (int*)p; p += (size_t)NBMAX * HB * 4;
    int* off    = (int*)p; p += (N + 1) * 4;
    int* esrc   = (int*)p; p += E * 4;
    unsigned* ebuf = (unsigned*)p; p += E * 4;

    unsigned char* Wt8_1a = Wt8All;
    unsigned char* Wt8_1b = Wt8All + 16384;
    unsigned char* Wt8_2a = Wt8All + 32768;
    unsigned char* Wt8_2b = Wt8All + 49152;

    float* out1 = (float*)d_out;
    float* out3 = out1 + (size_t)Gn * C_;
    float* outm = out3 + (size_t)Gn * D_;

    int nchunks  = (int)(NH / 8);
    int castBlk  = (nchunks + 255) / 256;
    int nBlocks  = (N + 255) / 256;
    int gatherBlk = (N * 16 + 255) / 256;
    int gemmBlk  = (N + 63) / 64;
    int chunkH   = (E + HB - 1) / HB;
    float invN = 1.0f / (float)N;

    int initBlk = castBlk + 4 + HB + nBlocks + 1;

    // 1. mega-init
    init_all<<<initBlk, 256, 0, stream>>>(x, xb, x8, castBlk, nchunks,
                                          W1a, W1b, W2a, W2b, Wt8All,
                                          dst, bpart, E, chunkH,
                                          batch, gstart, N, Gn, nBlocks,
                                          S1a, outm);
    // 2. bucket totals -> offsets + cursors
    scanp<<<1, 256, 0, stream>>>(bpart, boff, bcur, NB, E);
    // 3. bin edges
    bucket_bin<<<HB, 256, 0, stream>>>(src, dst, bcur, ebuf, E, NB, chunkH);
    // 4. per-bucket CSR fill
    bucket_fill<<<NB, 256, 0, stream>>>(ebuf, boff, off, esrc, N, NB, E);
    // 5-6. layer 1: gather -> U8 (fp8); gemm emits h8 (fp8) only
    gather_u<false><<<gatherBlk, 256, 0, stream>>>(xb, x8, off, esrc, eps1,
                                                   nullptr, nullptr, nullptr, nullptr, 0.f, U8, N);
    gemm2F<false><<<gemmBlk, 256, 0, stream>>>(U8, Wt8_1a, b1a, Wt8_1b, b1b,
                                               nullptr, h8, S1a, S2a, N);
    // 7-8. layer 2: gather (self+neighbors from h8, BN1 inline) -> U8; gemm emits bf16 Hp2
    gather_u<true><<<gatherBlk, 256, 0, stream>>>(nullptr, h8, off, esrc, eps2,
                                                  S1a, S2a, g1, be1, invN, U8, N);
    gemm2F<true><<<gemmBlk, 256, 0, stream>>>(U8, Wt8_2a, b2a, Wt8_2b, b2b,
                                              Hp2, nullptr, S1b, S2b, N);
    // 9. tail
    pool_tail<<<Gn, 512, 0, stream>>>(Hp2, S1b, S2b, g2, be2, invN, gstart,
                                      Wlin1, blin1, Wloss, bloss, degree,
                                      Wlin2, blin2, Wlin4, blin4,
                                      out1, out3, outm, C_, D_);
}